// Round 15
// baseline (353.296 us; speedup 1.0000x reference)
//
#include <hip/hip_runtime.h>
#include <math.h>

// NGP fused, round 12 design (fourth submission — rounds 12-14 never acquired a GPU):
// spatial counting-sort (64x64 bins) + quad/f16 tables + MFMA MLP.
// Evidence: r11 = 191.5us, TA-bound with L1-replay x2 (hot 2.8MB >> 32KB L1, random pts).
// Sort makes waves spatially coherent: quad gathers coalesce to few lines; per-bin hashed
// hot set (~20KB) goes L1-resident. Pipeline: build_tabs | memset hist -> hist -> scan ->
// scatter -> main(sorted ids). ws = 11,247,360B <= 11,404,512B proven available (r5).

typedef _Float16 f16x8 __attribute__((ext_vector_type(8)));
typedef float    f32x4 __attribute__((ext_vector_type(4)));

static constexpr int RESC[16] = {16,20,25,32,40,51,64,81,102,128,161,203,256,323,406,512};
static constexpr int QOFF[12] = {0,256,656,1281,2305,3905,6506,10602,17163,27567,43951,69872};
static constexpr int QTOT = 111081;
static constexpr size_t QBYTES = (size_t)QTOT * 16;            // 1,777,296
static constexpr size_t OFF_H16  = 1777408;                    // align(QBYTES,256)
static constexpr size_t OFF_HIST = OFF_H16 + 1048576;          // 2,825,984
static constexpr size_t OFF_CUR  = OFF_HIST + 16384;           // 2,842,368
static constexpr size_t OFF_SID  = OFF_CUR + 16384;            // 2,858,752
static constexpr int NB = 4096;                                // 64x64 bins
static constexpr int STRB = 80;   // LDS row stride: 64B feats + 4B id + pad

__device__ __forceinline__ float sigmoidf_(float a) { return 1.f / (1.f + __expf(-a)); }

__device__ __forceinline__ int bin_of(float2 c) {
    int bx = (int)(c.x * 64.f); bx = bx > 63 ? 63 : bx;
    int by = (int)(c.y * 64.f); by = by > 63 ? 63 : by;
    return by * 64 + bx;
}

// ---- prepass: quad tables (levels 0-11) + f16 hashed tables (12-15). r11-verified.
__global__ __launch_bounds__(256) void build_tabs(
    const float2* __restrict__ hf, uint4* __restrict__ quad, unsigned* __restrict__ h16)
{
    const int l = blockIdx.y;
    const int e = blockIdx.x * 256 + threadIdx.x;
    if (l < 12) {
        const int res = RESC[l];
        if (e >= res * res) return;
        const int y = e / res;
        const int x = e - y * res;
        const unsigned ay0 = 2654435761u * (unsigned)y;
        const unsigned ay1 = 2654435761u * (unsigned)(y + 1);
        const int h00 = (int)(((unsigned)x       ^ ay0) & 65535u);
        const int h10 = (int)(((unsigned)(x + 1) ^ ay0) & 65535u);
        const int h01 = (int)(((unsigned)x       ^ ay1) & 65535u);
        const int h11 = (int)(((unsigned)(x + 1) ^ ay1) & 65535u);
        const float2* t = hf + l * 65536;
        const float2 f00 = t[h00], f10 = t[h10], f01 = t[h01], f11 = t[h11];
        union { _Float16 h[8]; uint4 u; } pk;
        pk.h[0] = (_Float16)f00.x; pk.h[1] = (_Float16)f00.y;
        pk.h[2] = (_Float16)f10.x; pk.h[3] = (_Float16)f10.y;
        pk.h[4] = (_Float16)f01.x; pk.h[5] = (_Float16)f01.y;
        pk.h[6] = (_Float16)f11.x; pk.h[7] = (_Float16)f11.y;
        quad[QOFF[l] + e] = pk.u;
    } else {
        if (e >= 65536) return;
        const float2 v = hf[l * 65536 + e];
        union { _Float16 h[2]; unsigned u; } pk;
        pk.h[0] = (_Float16)v.x; pk.h[1] = (_Float16)v.y;
        h16[(l - 12) * 65536 + e] = pk.u;
    }
}

// ---- sort pass 1: LDS-aggregated histogram (64 blocks grid-stride)
__global__ __launch_bounds__(256) void hist_bins(
    const float2* __restrict__ x, int* __restrict__ hist, int M)
{
    __shared__ int lh[NB];
    for (int t = threadIdx.x; t < NB; t += 256) lh[t] = 0;
    __syncthreads();
    for (int i = blockIdx.x * 256 + threadIdx.x; i < M; i += gridDim.x * 256)
        atomicAdd(&lh[bin_of(x[i])], 1);
    __syncthreads();
    for (int t = threadIdx.x; t < NB; t += 256) {
        const int v = lh[t];
        if (v) atomicAdd(&hist[t], v);
    }
}

// ---- sort pass 2: exclusive scan of 4096 bins -> cursor (1 block, 1024 thr)
__global__ __launch_bounds__(1024) void scan_bins(
    const int* __restrict__ hist, int* __restrict__ cursor)
{
    __shared__ int ls[1024];
    const int t = threadIdx.x;
    const int h0 = hist[4*t], h1 = hist[4*t+1], h2 = hist[4*t+2], h3 = hist[4*t+3];
    const int s = h0 + h1 + h2 + h3;
    ls[t] = s;
    __syncthreads();
    for (int off = 1; off < 1024; off <<= 1) {
        const int v = (t >= off) ? ls[t - off] : 0;
        __syncthreads();
        ls[t] += v;
        __syncthreads();
    }
    const int excl = ls[t] - s;
    cursor[4*t]   = excl;
    cursor[4*t+1] = excl + h0;
    cursor[4*t+2] = excl + h0 + h1;
    cursor[4*t+3] = excl + h0 + h1 + h2;
}

// ---- sort pass 3: scatter point ids into bin-sorted order
__global__ __launch_bounds__(256) void scatter_pts(
    const float2* __restrict__ x, int* __restrict__ cursor, int* __restrict__ sid, int M)
{
    const int i = blockIdx.x * 256 + threadIdx.x;
    if (i >= M) return;
    const int pos = atomicAdd(&cursor[bin_of(x[i])], 1);
    sid[pos] = i;
}

__device__ __forceinline__ f16x8 load_wfrag(const float* __restrict__ w, int row, int g, bool valid) {
    f16x8 a;
    if (valid) {
        const float4 lo = *reinterpret_cast<const float4*>(w + row * 32 + g * 8);
        const float4 hi = *reinterpret_cast<const float4*>(w + row * 32 + g * 8 + 4);
        a[0]=(_Float16)lo.x; a[1]=(_Float16)lo.y; a[2]=(_Float16)lo.z; a[3]=(_Float16)lo.w;
        a[4]=(_Float16)hi.x; a[5]=(_Float16)hi.y; a[6]=(_Float16)hi.z; a[7]=(_Float16)hi.w;
    } else {
#pragma unroll
        for (int j = 0; j < 8; ++j) a[j] = (_Float16)0.f;
    }
    return a;
}

// ---- main: SORTED=1 reads sid[i]/x[id], writes out[id]; SORTED=0 = r11 behavior
template<int SORTED>
__global__ __launch_bounds__(256) void ngp_mfma3(
    const float2* __restrict__ x,
    const int*    __restrict__ sid,
    const uint4*  __restrict__ quad,
    const unsigned* __restrict__ h16,
    const float*  __restrict__ w1, const float* __restrict__ w2, const float* __restrict__ w3,
    float* __restrict__ out)
{
    __shared__ char smem[4][64 * STRB];
    const int tid  = threadIdx.x;
    const int wv   = tid >> 6;
    const int lane = tid & 63;
    const int r    = lane & 15;
    const int g    = lane >> 4;
    char* sb = smem[wv];

    const int slot = blockIdx.x * 256 + tid;
    const int id = SORTED ? sid[slot] : slot;
    const float2 c = x[id];
    *reinterpret_cast<int*>(sb + lane * STRB + 64) = id;   // byte 64: id for epilogue

    // ---- phase 1: all 28 gathers issued before consumption
    uint4 q[12];
    float wxa[16], wya[16];
#pragma unroll
    for (int l = 0; l < 12; ++l) {
        const float rf = (float)RESC[l];
        const float xs = c.x * rf, ys = c.y * rf;
        const float fx = floorf(xs), fy = floorf(ys);
        wxa[l] = xs - fx; wya[l] = ys - fy;
        q[l] = quad[QOFF[l] + (int)fy * RESC[l] + (int)fx];
    }
    unsigned u00[4], u01[4], u10[4], u11[4];
#pragma unroll
    for (int t = 0; t < 4; ++t) {
        const int l = 12 + t;
        const float rf = (float)RESC[l];
        const float xs = c.x * rf, ys = c.y * rf;
        const float fx = floorf(xs), fy = floorf(ys);
        wxa[l] = xs - fx; wya[l] = ys - fy;
        const int xi = (int)fx, yi = (int)fy;
        const unsigned ay0 = 2654435761u * (unsigned)yi;
        const unsigned ay1 = 2654435761u * (unsigned)(yi + 1);
        const unsigned* tb = h16 + t * 65536;
        u00[t] = tb[((unsigned)xi       ^ ay0) & 65535u];
        u01[t] = tb[((unsigned)xi       ^ ay1) & 65535u];
        u10[t] = tb[((unsigned)(xi + 1) ^ ay0) & 65535u];
        u11[t] = tb[((unsigned)(xi + 1) ^ ay1) & 65535u];
    }

    // ---- phase 2: bilerp -> f16 feat pairs in LDS row
    unsigned* srow = reinterpret_cast<unsigned*>(sb + lane * STRB);
#pragma unroll
    for (int l = 0; l < 12; ++l) {
        union { uint4 u; _Float16 h[8]; } pk; pk.u = q[l];
        const float wx = wxa[l], wy = wya[l];
        const float e0 = fmaf(wx, (float)pk.h[2] - (float)pk.h[0], (float)pk.h[0]);
        const float e1 = fmaf(wx, (float)pk.h[3] - (float)pk.h[1], (float)pk.h[1]);
        const float o0 = fmaf(wx, (float)pk.h[6] - (float)pk.h[4], (float)pk.h[4]);
        const float o1 = fmaf(wx, (float)pk.h[7] - (float)pk.h[5], (float)pk.h[5]);
        const float sc = (float)(1u << l);
        union { _Float16 h[2]; unsigned u; } o;
        o.h[0] = (_Float16)(fmaf(wy, o0 - e0, e0) * sc);
        o.h[1] = (_Float16)(fmaf(wy, o1 - e1, e1) * sc);
        srow[l] = o.u;
    }
#pragma unroll
    for (int t = 0; t < 4; ++t) {
        const int l = 12 + t;
        union { unsigned u; _Float16 h[2]; } a, b, cc, d;
        a.u = u00[t]; b.u = u10[t]; cc.u = u01[t]; d.u = u11[t];
        const float wx = wxa[l], wy = wya[l];
        const float e0 = fmaf(wx, (float)b.h[0] - (float)a.h[0], (float)a.h[0]);
        const float e1 = fmaf(wx, (float)b.h[1] - (float)a.h[1], (float)a.h[1]);
        const float o0 = fmaf(wx, (float)d.h[0] - (float)cc.h[0], (float)cc.h[0]);
        const float o1 = fmaf(wx, (float)d.h[1] - (float)cc.h[1], (float)cc.h[1]);
        const float sc = (float)(1u << l);
        union { _Float16 h[2]; unsigned u; } o;
        o.h[0] = (_Float16)(fmaf(wy, o0 - e0, e0) * sc);
        o.h[1] = (_Float16)(fmaf(wy, o1 - e1, e1) * sc);
        srow[l] = o.u;
    }

    // ---- MFMA MLP (r7/r11-verified structure)
    f16x8 a1[2], a2[2], a3;
    a1[0] = load_wfrag(w1, r,      g, true);
    a1[1] = load_wfrag(w1, 16 + r, g, true);
    a2[0] = load_wfrag(w2, r,      g, true);
    a2[1] = load_wfrag(w2, 16 + r, g, true);
    a3    = load_wfrag(w3, r,      g, r < 3);

    const f32x4 zero = {0.f, 0.f, 0.f, 0.f};
    f16x8 bfr[4];
#pragma unroll
    for (int pt = 0; pt < 4; ++pt)
        bfr[pt] = *reinterpret_cast<const f16x8*>(sb + (pt * 16 + r) * STRB + g * 16);
#pragma unroll
    for (int nt = 0; nt < 2; ++nt) {
#pragma unroll
        for (int pt = 0; pt < 4; ++pt) {
            f32x4 acc = __builtin_amdgcn_mfma_f32_16x16x32_f16(a1[nt], bfr[pt], zero, 0, 0, 0);
            union { _Float16 h[4]; uint2 u; } pk;
#pragma unroll
            for (int qq = 0; qq < 4; ++qq) pk.h[qq] = (_Float16)fmaxf(acc[qq], 0.f);
            *reinterpret_cast<uint2*>(sb + (pt * 16 + r) * STRB + nt * 32 + g * 8) = pk.u;
        }
    }
#pragma unroll
    for (int pt = 0; pt < 4; ++pt)
        bfr[pt] = *reinterpret_cast<const f16x8*>(sb + (pt * 16 + r) * STRB + g * 16);
#pragma unroll
    for (int nt = 0; nt < 2; ++nt) {
#pragma unroll
        for (int pt = 0; pt < 4; ++pt) {
            f32x4 acc = __builtin_amdgcn_mfma_f32_16x16x32_f16(a2[nt], bfr[pt], zero, 0, 0, 0);
            union { _Float16 h[4]; uint2 u; } pk;
#pragma unroll
            for (int qq = 0; qq < 4; ++qq) pk.h[qq] = (_Float16)fmaxf(acc[qq], 0.f);
            *reinterpret_cast<uint2*>(sb + (pt * 16 + r) * STRB + nt * 32 + g * 8) = pk.u;
        }
    }
#pragma unroll
    for (int pt = 0; pt < 4; ++pt)
        bfr[pt] = *reinterpret_cast<const f16x8*>(sb + (pt * 16 + r) * STRB + g * 16);
#pragma unroll
    for (int pt = 0; pt < 4; ++pt) {
        f32x4 acc = __builtin_amdgcn_mfma_f32_16x16x32_f16(a3, bfr[pt], zero, 0, 0, 0);
        if (g == 0) {
            const int idp = *reinterpret_cast<const int*>(sb + (pt * 16 + r) * STRB + 64);
            out[idp * 3 + 0] = sigmoidf_(acc[0]);
            out[idp * 3 + 1] = sigmoidf_(acc[1]);
            out[idp * 3 + 2] = sigmoidf_(acc[2]);
        }
    }
}

// ---- scalar fallback (direct order, fp32)
__global__ __launch_bounds__(256) void ngp_scalar(
    const float2* __restrict__ x, const float2* __restrict__ hf,
    const float* __restrict__ w1, const float* __restrict__ w2,
    const float* __restrict__ w3, float* __restrict__ out, int base, int M)
{
    const int i = base + blockIdx.x * 256 + threadIdx.x;
    if (i >= M) return;
    const float2 c = x[i];
    float feats[32];
#pragma unroll
    for (int l = 0; l < 16; ++l) {
        const float rf = (float)RESC[l];
        const float xs = c.x * rf, ys = c.y * rf;
        const float fx = floorf(xs), fy = floorf(ys);
        const int xi = (int)fx, yi = (int)fy;
        const float wx = xs - fx, wy = ys - fy;
        const unsigned ay0 = 2654435761u * (unsigned)yi;
        const unsigned ay1 = 2654435761u * (unsigned)(yi + 1);
        const int h00 = (int)(((unsigned)xi     ^ ay0) & 65535u);
        const int h01 = (int)(((unsigned)xi     ^ ay1) & 65535u);
        const int h10 = (int)(((unsigned)(xi+1) ^ ay0) & 65535u);
        const int h11 = (int)(((unsigned)(xi+1) ^ ay1) & 65535u);
        const float2* t = hf + l * 65536;
        const float2 f00 = t[h00], f01 = t[h01], f10 = t[h10], f11 = t[h11];
        const float e0 = fmaf(wx, f10.x - f00.x, f00.x);
        const float e1 = fmaf(wx, f10.y - f00.y, f00.y);
        const float o0 = fmaf(wx, f11.x - f01.x, f01.x);
        const float o1 = fmaf(wx, f11.y - f01.y, f01.y);
        const float sc = (float)(1u << l);
        feats[2*l]   = fmaf(wy, o0 - e0, e0) * sc;
        feats[2*l+1] = fmaf(wy, o1 - e1, e1) * sc;
    }
    float h1[32];
#pragma unroll
    for (int j = 0; j < 32; ++j) {
        float acc = 0.f;
#pragma unroll
        for (int k = 0; k < 32; ++k) acc = fmaf(feats[k], w1[j*32+k], acc);
        h1[j] = fmaxf(acc, 0.f);
    }
    float h2[32];
#pragma unroll
    for (int j = 0; j < 32; ++j) {
        float acc = 0.f;
#pragma unroll
        for (int k = 0; k < 32; ++k) acc = fmaf(h1[k], w2[j*32+k], acc);
        h2[j] = fmaxf(acc, 0.f);
    }
#pragma unroll
    for (int o = 0; o < 3; ++o) {
        float acc = 0.f;
#pragma unroll
        for (int k = 0; k < 32; ++k) acc = fmaf(h2[k], w3[o*32+k], acc);
        out[3*i + o] = 1.f / (1.f + __expf(-acc));
    }
}

extern "C" void kernel_launch(void* const* d_in, const int* in_sizes, int n_in,
                              void* d_out, int out_size, void* d_ws, size_t ws_size,
                              hipStream_t stream) {
    const float2* x  = (const float2*)d_in[0];
    const float2* hf = (const float2*)d_in[1];
    const float*  w1 = (const float*)d_in[2];
    const float*  w2 = (const float*)d_in[3];
    const float*  w3 = (const float*)d_in[4];
    float* out = (float*)d_out;
    const int M = in_sizes[0] / 2;

    const size_t ws_sort = OFF_SID + (size_t)M * 4;   // 11,247,360 @ M=2^21
    const size_t ws_tabs = OFF_HIST;                  // tables only

    if (ws_size >= ws_tabs) {
        uint4*    quad   = (uint4*)d_ws;
        unsigned* h16    = (unsigned*)((char*)d_ws + OFF_H16);
        build_tabs<<<dim3(256, 16), 256, 0, stream>>>(hf, quad, h16);

        const int full = M / 256;
        const int base = full * 256;
        if (ws_size >= ws_sort && base == M) {
            int* hist   = (int*)((char*)d_ws + OFF_HIST);
            int* cursor = (int*)((char*)d_ws + OFF_CUR);
            int* sid    = (int*)((char*)d_ws + OFF_SID);
            hipMemsetAsync(hist, 0, NB * sizeof(int), stream);
            hist_bins<<<64, 256, 0, stream>>>(x, hist, M);
            scan_bins<<<1, 1024, 0, stream>>>(hist, cursor);
            scatter_pts<<<(M + 255) / 256, 256, 0, stream>>>(x, cursor, sid, M);
            ngp_mfma3<1><<<full, 256, 0, stream>>>(x, sid, quad, h16, w1, w2, w3, out);
        } else {
            if (full > 0)
                ngp_mfma3<0><<<full, 256, 0, stream>>>(x, nullptr, quad, h16, w1, w2, w3, out);
            if (M - base > 0)
                ngp_scalar<<<((M - base) + 255) / 256, 256, 0, stream>>>(x, hf, w1, w2, w3, out, base, M);
        }
    } else {
        ngp_scalar<<<(M + 255) / 256, 256, 0, stream>>>(x, hf, w1, w2, w3, out, 0, M);
    }
}